// Round 1
// baseline (590.587 us; speedup 1.0000x reference)
//
#include <hip/hip_runtime.h>

#define BATCH  4096
#define HIDDEN 2048
#define INPUT  2048
#define KDIM   4096   // INPUT + HIDDEN (fused K)
#define NDIM   8192   // 4 * HIDDEN (fused gate dim)

#define BM 128
#define BN 128
#define BK 32

typedef __attribute__((ext_vector_type(8))) short short8;
typedef __attribute__((ext_vector_type(4))) float float4v;

// ---------- helpers ----------

__device__ __forceinline__ unsigned short f2bf(float f) {
    union { float f; unsigned u; } v; v.f = f;
    unsigned r = v.u + 0x7FFFu + ((v.u >> 16) & 1u);   // round-to-nearest-even
    return (unsigned short)(r >> 16);
}

__device__ __forceinline__ void gl2lds16(const unsigned short* g, unsigned short* l) {
    // async global->LDS, 16 B per lane; LDS dest is wave-uniform base + lane*16
    __builtin_amdgcn_global_load_lds(
        (const __attribute__((address_space(1))) unsigned int*)g,
        (__attribute__((address_space(3))) unsigned int*)l,
        16, 0, 0);
}

__device__ __forceinline__ float sigm(float x) {
    return 1.0f / (1.0f + __expf(-x));
}
__device__ __forceinline__ float tanh_fast(float x) {
    return 2.0f / (1.0f + __expf(-2.0f * x)) - 1.0f;
}

// ---------- kernel 1: pack [x | h] -> bf16, row-major K-contiguous ----------

__global__ void pack_x_kernel(const float* __restrict__ x, const float* __restrict__ h,
                              unsigned short* __restrict__ Xb) {
    int idx = blockIdx.x * 256 + threadIdx.x;   // one 8-element group per thread
    int b  = idx >> 9;                          // 512 groups per row (4096/8)
    int ko = idx & 511;
    const float* src = (ko < 256) ? (x + (size_t)b * INPUT  + (size_t)ko * 8)
                                  : (h + (size_t)b * HIDDEN + (size_t)(ko - 256) * 8);
    float4 v0 = *(const float4*)(src);
    float4 v1 = *(const float4*)(src + 4);
    union { unsigned short us[8]; uint4 v; } o;
    o.us[0] = f2bf(v0.x); o.us[1] = f2bf(v0.y); o.us[2] = f2bf(v0.z); o.us[3] = f2bf(v0.w);
    o.us[4] = f2bf(v1.x); o.us[5] = f2bf(v1.y); o.us[6] = f2bf(v1.z); o.us[7] = f2bf(v1.w);
    *(uint4*)(Xb + (size_t)b * KDIM + (size_t)ko * 8) = o.v;
}

// ---------- kernel 2: pack/transpose W' -> bf16 B^T layout (N x K, K-contiguous) ----------
// W'[k][n], n = g*2048 + j;  k<2048 -> w_ih[g][k][j], else w_hh[g][k-2048][j]
// Wt[n][k] = bf16(W'[k][n])

__global__ void pack_w_kernel(const float* __restrict__ w_ih, const float* __restrict__ w_hh,
                              unsigned short* __restrict__ Wt) {
    __shared__ float tile[64][33];
    int k0 = blockIdx.x * 64;    // K tile (never straddles the 2048 boundary)
    int n0 = blockIdx.y * 32;    // N tile
    int g  = n0 >> 11;
    int j0 = n0 & 2047;
    const float* src = (k0 < INPUT)
        ? (w_ih + (size_t)g * INPUT  * HIDDEN + (size_t)k0 * HIDDEN + j0)
        : (w_hh + (size_t)g * HIDDEN * HIDDEN + (size_t)(k0 - INPUT) * HIDDEN + j0);

    int tcol = threadIdx.x & 31;      // j within tile
    int trow = threadIdx.x >> 5;      // 0..7
#pragma unroll
    for (int p = 0; p < 8; ++p)
        tile[trow + p * 8][tcol] = src[(size_t)(trow + p * 8) * HIDDEN + tcol];
    __syncthreads();

    int tk = threadIdx.x & 63;        // k within tile
    int tn = threadIdx.x >> 6;        // 0..3
#pragma unroll
    for (int p = 0; p < 8; ++p)
        Wt[(size_t)(n0 + tn + p * 4) * KDIM + k0 + tk] = f2bf(tile[tk][tn + p * 4]);
}

// ---------- kernel 3: bf16 MFMA GEMM, C[M=4096][N=8192] fp32 gates ----------
// A: Xb [M][K] bf16 (k-contig), B: Wt [N][K] bf16 (k-contig, i.e. B^T)

__global__ __launch_bounds__(256, 2)
void gemm_kernel(const unsigned short* __restrict__ A,
                 const unsigned short* __restrict__ B,
                 float* __restrict__ C) {
    __shared__ unsigned short As[BM * BK];   // [m][k], rows of 64 B
    __shared__ unsigned short Bs[BN * BK];   // [n][k]

    const int tid  = threadIdx.x;
    const int m0   = blockIdx.y * BM;
    const int n0   = blockIdx.x * BN;
    const int wave = tid >> 6;
    const int lane = tid & 63;
    const int ln   = lane & 15;
    const int kq   = lane >> 4;             // 0..3
    const int wm   = (wave >> 1) * 64;
    const int wn   = (wave & 1) * 64;

    // staging: tile = 512 segments of 16 B; thread handles segments tid, tid+256
    const int s0 = tid, s1 = tid + 256;
    const unsigned short* gA0 = A + (size_t)(m0 + (s0 >> 2)) * KDIM + (s0 & 3) * 8;
    const unsigned short* gA1 = A + (size_t)(m0 + (s1 >> 2)) * KDIM + (s1 & 3) * 8;
    const unsigned short* gB0 = B + (size_t)(n0 + (s0 >> 2)) * KDIM + (s0 & 3) * 8;
    const unsigned short* gB1 = B + (size_t)(n0 + (s1 >> 2)) * KDIM + (s1 & 3) * 8;
    unsigned short* lA0 = As + s0 * 8;
    unsigned short* lA1 = As + s1 * 8;
    unsigned short* lB0 = Bs + s0 * 8;
    unsigned short* lB1 = Bs + s1 * 8;

    float4v acc[4][4];
#pragma unroll
    for (int i = 0; i < 4; ++i)
#pragma unroll
        for (int j = 0; j < 4; ++j)
            acc[i][j] = (float4v){0.f, 0.f, 0.f, 0.f};

    const int a_off = (wm + ln) * BK + kq * 8;   // + mi*16*BK
    const int b_off = (wn + ln) * BK + kq * 8;   // + ni*16*BK

    for (int kt = 0; kt < KDIM / BK; ++kt) {
        const int ko = kt * BK;
        gl2lds16(gA0 + ko, lA0);
        gl2lds16(gA1 + ko, lA1);
        gl2lds16(gB0 + ko, lB0);
        gl2lds16(gB1 + ko, lB1);
        __syncthreads();   // drains vmcnt -> staged data visible

        short8 af[4], bf[4];
#pragma unroll
        for (int mi = 0; mi < 4; ++mi)
            af[mi] = *(const short8*)(As + a_off + mi * 16 * BK);
#pragma unroll
        for (int ni = 0; ni < 4; ++ni)
            bf[ni] = *(const short8*)(Bs + b_off + ni * 16 * BK);

#pragma unroll
        for (int mi = 0; mi < 4; ++mi)
#pragma unroll
            for (int ni = 0; ni < 4; ++ni)
                acc[mi][ni] = __builtin_amdgcn_mfma_f32_16x16x32_bf16(
                    af[mi], bf[ni], acc[mi][ni], 0, 0, 0);

        __syncthreads();   // protect LDS before next stage
    }

    // C/D layout: col = lane&15, row = (lane>>4)*4 + reg
#pragma unroll
    for (int mi = 0; mi < 4; ++mi) {
#pragma unroll
        for (int ni = 0; ni < 4; ++ni) {
            int col  = n0 + wn + ni * 16 + ln;
            int rowb = m0 + wm + mi * 16 + kq * 4;
#pragma unroll
            for (int j = 0; j < 4; ++j)
                C[(size_t)(rowb + j) * NDIM + col] = acc[mi][ni][j];
        }
    }
}

// ---------- kernel 4: LSTM elementwise epilogue ----------

__global__ void lstm_epilogue_kernel(const float* __restrict__ Cg, const float* __restrict__ c,
                                     const float* __restrict__ b_ih, const float* __restrict__ b_hh,
                                     float* __restrict__ out) {
    int idx = blockIdx.x * 256 + threadIdx.x;   // one 4-element group
    int b = idx >> 9;                           // 512 groups per row (2048/4)
    int j = (idx & 511) * 4;

    const float* row = Cg + (size_t)b * NDIM;
    float4 g0 = *(const float4*)(row + j);
    float4 g1 = *(const float4*)(row + HIDDEN + j);
    float4 g2 = *(const float4*)(row + 2 * HIDDEN + j);
    float4 g3 = *(const float4*)(row + 3 * HIDDEN + j);

    float4 bi0 = *(const float4*)(b_ih + j);
    float4 bi1 = *(const float4*)(b_ih + HIDDEN + j);
    float4 bi2 = *(const float4*)(b_ih + 2 * HIDDEN + j);
    float4 bi3 = *(const float4*)(b_ih + 3 * HIDDEN + j);
    float4 bh0 = *(const float4*)(b_hh + j);
    float4 bh1 = *(const float4*)(b_hh + HIDDEN + j);
    float4 bh2 = *(const float4*)(b_hh + 2 * HIDDEN + j);
    float4 bh3 = *(const float4*)(b_hh + 3 * HIDDEN + j);

    float4 cv = *(const float4*)(c + (size_t)b * HIDDEN + j);

    float4 hn, cn;
    {
        float ig = sigm(g0.x + bi0.x + bh0.x);
        float fg = sigm(g1.x + bi1.x + bh1.x);
        float cg = tanh_fast(g2.x + bi2.x + bh2.x);
        float og = sigm(g3.x + bi3.x + bh3.x);
        cn.x = fg * cv.x + ig * cg;
        hn.x = og * tanh_fast(cn.x);
    }
    {
        float ig = sigm(g0.y + bi0.y + bh0.y);
        float fg = sigm(g1.y + bi1.y + bh1.y);
        float cg = tanh_fast(g2.y + bi2.y + bh2.y);
        float og = sigm(g3.y + bi3.y + bh3.y);
        cn.y = fg * cv.y + ig * cg;
        hn.y = og * tanh_fast(cn.y);
    }
    {
        float ig = sigm(g0.z + bi0.z + bh0.z);
        float fg = sigm(g1.z + bi1.z + bh1.z);
        float cg = tanh_fast(g2.z + bi2.z + bh2.z);
        float og = sigm(g3.z + bi3.z + bh3.z);
        cn.z = fg * cv.z + ig * cg;
        hn.z = og * tanh_fast(cn.z);
    }
    {
        float ig = sigm(g0.w + bi0.w + bh0.w);
        float fg = sigm(g1.w + bi1.w + bh1.w);
        float cg = tanh_fast(g2.w + bi2.w + bh2.w);
        float og = sigm(g3.w + bi3.w + bh3.w);
        cn.w = fg * cv.w + ig * cg;
        hn.w = og * tanh_fast(cn.w);
    }

    size_t o = (size_t)b * HIDDEN + j;
    *(float4*)(out + o) = hn;                                   // h_new
    *(float4*)(out + (size_t)BATCH * HIDDEN + o) = cn;          // c_new
}

// ---------- launcher ----------

extern "C" void kernel_launch(void* const* d_in, const int* in_sizes, int n_in,
                              void* d_out, int out_size, void* d_ws, size_t ws_size,
                              hipStream_t stream) {
    const float* x    = (const float*)d_in[0];
    const float* h    = (const float*)d_in[1];
    const float* c    = (const float*)d_in[2];
    const float* w_ih = (const float*)d_in[3];
    const float* w_hh = (const float*)d_in[4];
    const float* b_ih = (const float*)d_in[5];
    const float* b_hh = (const float*)d_in[6];
    float* out = (float*)d_out;

    const size_t XB_BYTES = (size_t)BATCH * KDIM * 2;   // 32 MB
    const size_t WT_BYTES = (size_t)NDIM * KDIM * 2;    // 64 MB
    unsigned short* Xb = (unsigned short*)d_ws;
    unsigned short* Wt = (unsigned short*)((char*)d_ws + XB_BYTES);
    float*          Cg = (float*)((char*)d_ws + XB_BYTES + WT_BYTES);  // 128 MB

    hipLaunchKernelGGL(pack_x_kernel, dim3((size_t)BATCH * KDIM / 8 / 256), dim3(256), 0, stream,
                       x, h, Xb);
    hipLaunchKernelGGL(pack_w_kernel, dim3(KDIM / 64, NDIM / 32), dim3(256), 0, stream,
                       w_ih, w_hh, Wt);
    hipLaunchKernelGGL(gemm_kernel, dim3(NDIM / BN, BATCH / BM), dim3(256), 0, stream,
                       Xb, Wt, Cg);
    hipLaunchKernelGGL(lstm_epilogue_kernel, dim3((size_t)BATCH * HIDDEN / 4 / 256), dim3(256), 0, stream,
                       Cg, c, b_ih, b_hh, out);
}

// Round 2
// 565.043 us; speedup vs baseline: 1.0452x; 1.0452x over previous
//
#include <hip/hip_runtime.h>

#define BATCH  4096
#define HIDDEN 2048
#define INPUT  2048
#define KDIM   4096   // INPUT + HIDDEN (fused K)
#define NDIM   8192   // 4 * HIDDEN (fused gate dim), gate-interleaved: n' = 4*j + g
#define BM 128
#define BN 128
#define BK 32

typedef __attribute__((ext_vector_type(8))) short short8;
typedef __attribute__((ext_vector_type(4))) float float4v;

// ---------- helpers ----------

__device__ __forceinline__ unsigned short f2bf(float f) {
    union { float f; unsigned u; } v; v.f = f;
    unsigned r = v.u + 0x7FFFu + ((v.u >> 16) & 1u);   // round-to-nearest-even
    return (unsigned short)(r >> 16);
}

__device__ __forceinline__ void gl2lds16(const unsigned short* g, unsigned short* l) {
    __builtin_amdgcn_global_load_lds(
        (const __attribute__((address_space(1))) unsigned int*)g,
        (__attribute__((address_space(3))) unsigned int*)l,
        16, 0, 0);
}

__device__ __forceinline__ float sigm(float x) {
    return 1.0f / (1.0f + __expf(-x));
}
__device__ __forceinline__ float tanh_fast(float x) {
    return 2.0f / (1.0f + __expf(-2.0f * x)) - 1.0f;
}

// ---------- kernel 1: pack [x | h] -> bf16, row-major K-contiguous ----------

__global__ void pack_x_kernel(const float* __restrict__ x, const float* __restrict__ h,
                              unsigned short* __restrict__ Xb) {
    int idx = blockIdx.x * 256 + threadIdx.x;   // one 8-element group per thread
    int b  = idx >> 9;                          // 512 groups per row (4096/8)
    int ko = idx & 511;
    const float* src = (ko < 256) ? (x + (size_t)b * INPUT  + (size_t)ko * 8)
                                  : (h + (size_t)b * HIDDEN + (size_t)(ko - 256) * 8);
    float4 v0 = *(const float4*)(src);
    float4 v1 = *(const float4*)(src + 4);
    union { unsigned short us[8]; uint4 v; } o;
    o.us[0] = f2bf(v0.x); o.us[1] = f2bf(v0.y); o.us[2] = f2bf(v0.z); o.us[3] = f2bf(v0.w);
    o.us[4] = f2bf(v1.x); o.us[5] = f2bf(v1.y); o.us[6] = f2bf(v1.z); o.us[7] = f2bf(v1.w);
    *(uint4*)(Xb + (size_t)b * KDIM + (size_t)ko * 8) = o.v;
}

// ---------- kernel 2: pack/transpose W' -> bf16 B^T, GATE-INTERLEAVED ----------
// source col n_src = g*2048 + j  (k<2048 -> w_ih[g][k][j], else w_hh[g][k-2048][j])
// dest row  n'    = 4*j + g ;  Wt[n'][k] = bf16(W'[k][n_src]), k-contiguous

__global__ void pack_w_kernel(const float* __restrict__ w_ih, const float* __restrict__ w_hh,
                              unsigned short* __restrict__ Wt) {
    __shared__ float tile[64][33];
    int k0 = blockIdx.x * 64;        // K tile (never straddles the 2048 boundary)
    int n0 = blockIdx.y * 32;        // source-N tile (never straddles a gate boundary)
    int g  = n0 >> 11;
    int j0 = n0 & 2047;
    const float* src = (k0 < INPUT)
        ? (w_ih + (size_t)g * INPUT  * HIDDEN + (size_t)k0 * HIDDEN + j0)
        : (w_hh + (size_t)g * HIDDEN * HIDDEN + (size_t)(k0 - INPUT) * HIDDEN + j0);

    int tcol = threadIdx.x & 31;      // j within tile
    int trow = threadIdx.x >> 5;      // 0..7
#pragma unroll
    for (int p = 0; p < 8; ++p)
        tile[trow + p * 8][tcol] = src[(size_t)(trow + p * 8) * HIDDEN + tcol];
    __syncthreads();

    int tk = threadIdx.x & 63;        // k within tile
    int tn = threadIdx.x >> 6;        // 0..3
#pragma unroll
    for (int p = 0; p < 8; ++p) {
        int j = j0 + tn + p * 4;
        Wt[(size_t)(4 * j + g) * KDIM + k0 + tk] = f2bf(tile[tk][tn + p * 4]);
    }
}

// ---------- kernel 3: bf16 MFMA GEMM + fused LSTM epilogue ----------
// A: Xb [M][K] bf16 (k-contig), B: Wt [N'][K] bf16 (k-contig, gate-interleaved)
// epilogue: quad-transpose gathers 4 gates/lane -> sigmoid/tanh -> h_new, c_new

__global__ __launch_bounds__(256, 2)
void gemm_kernel(const unsigned short* __restrict__ A,
                 const unsigned short* __restrict__ B,
                 const float* __restrict__ c,
                 const float* __restrict__ b_ih,
                 const float* __restrict__ b_hh,
                 float* __restrict__ out) {
    __shared__ unsigned short As[BM * BK];   // [m][k], rows of 64 B
    __shared__ unsigned short Bs[BN * BK];   // [n'][k]

    const int tid  = threadIdx.x;
    const int m0   = blockIdx.y * BM;
    const int n0   = blockIdx.x * BN;
    const int wave = tid >> 6;
    const int lane = tid & 63;
    const int ln   = lane & 15;
    const int kq   = lane >> 4;             // 0..3
    const int wm   = (wave >> 1) * 64;
    const int wn   = (wave & 1) * 64;

    // staging: tile = 512 segments of 16 B; thread handles segments tid, tid+256
    const int s0 = tid, s1 = tid + 256;
    const unsigned short* gA0 = A + (size_t)(m0 + (s0 >> 2)) * KDIM + (s0 & 3) * 8;
    const unsigned short* gA1 = A + (size_t)(m0 + (s1 >> 2)) * KDIM + (s1 & 3) * 8;
    const unsigned short* gB0 = B + (size_t)(n0 + (s0 >> 2)) * KDIM + (s0 & 3) * 8;
    const unsigned short* gB1 = B + (size_t)(n0 + (s1 >> 2)) * KDIM + (s1 & 3) * 8;
    unsigned short* lA0 = As + s0 * 8;
    unsigned short* lA1 = As + s1 * 8;
    unsigned short* lB0 = Bs + s0 * 8;
    unsigned short* lB1 = Bs + s1 * 8;

    float4v acc[4][4];
#pragma unroll
    for (int i = 0; i < 4; ++i)
#pragma unroll
        for (int j = 0; j < 4; ++j)
            acc[i][j] = (float4v){0.f, 0.f, 0.f, 0.f};

    const int a_off = (wm + ln) * BK + kq * 8;   // + mi*16*BK
    const int b_off = (wn + ln) * BK + kq * 8;   // + ni*16*BK

    for (int kt = 0; kt < KDIM / BK; ++kt) {
        const int ko = kt * BK;
        gl2lds16(gA0 + ko, lA0);
        gl2lds16(gA1 + ko, lA1);
        gl2lds16(gB0 + ko, lB0);
        gl2lds16(gB1 + ko, lB1);
        __syncthreads();

        short8 af[4], bfr[4];
#pragma unroll
        for (int mi = 0; mi < 4; ++mi)
            af[mi] = *(const short8*)(As + a_off + mi * 16 * BK);
#pragma unroll
        for (int ni = 0; ni < 4; ++ni)
            bfr[ni] = *(const short8*)(Bs + b_off + ni * 16 * BK);

#pragma unroll
        for (int mi = 0; mi < 4; ++mi)
#pragma unroll
            for (int ni = 0; ni < 4; ++ni)
                acc[mi][ni] = __builtin_amdgcn_mfma_f32_16x16x32_bf16(
                    af[mi], bfr[ni], acc[mi][ni], 0, 0, 0);

        __syncthreads();
    }

    // ---- fused epilogue ----
    // C/D layout: col = ln, row = kq*4 + reg. col n' = 4*j + g with g = ln&3.
    // Quad transpose (lanes q=0..3 within a quad, shfl_xor 1 then 2):
    //   after: lane q holds gates g=0..3 (in regs) of row-offset kq*4+q.
    const int q = lane & 3;            // gate index pre-transpose, row sub-offset post
    const int t = (lane & 15) >> 2;    // j sub-offset
    const size_t HB = (size_t)BATCH * HIDDEN;

#pragma unroll
    for (int ni = 0; ni < 4; ++ni) {
        const int jg = ((n0 + wn + ni * 16) >> 2) + t;
        const float b0 = b_ih[jg]              + b_hh[jg];
        const float b1 = b_ih[HIDDEN + jg]     + b_hh[HIDDEN + jg];
        const float b2 = b_ih[2 * HIDDEN + jg] + b_hh[2 * HIDDEN + jg];
        const float b3 = b_ih[3 * HIDDEN + jg] + b_hh[3 * HIDDEN + jg];
#pragma unroll
        for (int mi = 0; mi < 4; ++mi) {
            float4v v = acc[mi][ni];
            // round 1: xor 1, exchange reg pairs (0,1) and (2,3)
            float t1 = __shfl_xor((q & 1) ? v[0] : v[1], 1);
            float t2 = __shfl_xor((q & 1) ? v[2] : v[3], 1);
            v[0] = (q & 1) ? t1 : v[0];
            v[1] = (q & 1) ? v[1] : t1;
            v[2] = (q & 1) ? t2 : v[2];
            v[3] = (q & 1) ? v[3] : t2;
            // round 2: xor 2, exchange reg pairs (0,2) and (1,3)
            float t3 = __shfl_xor((q & 2) ? v[0] : v[2], 2);
            float t4 = __shfl_xor((q & 2) ? v[1] : v[3], 2);
            v[0] = (q & 2) ? t3 : v[0];
            v[1] = (q & 2) ? t4 : v[1];
            v[2] = (q & 2) ? v[2] : t3;
            v[3] = (q & 2) ? v[3] : t4;

            const int row = m0 + wm + mi * 16 + kq * 4 + q;
            const float ig = sigm(v[0] + b0);
            const float fg = sigm(v[1] + b1);
            const float cg = tanh_fast(v[2] + b2);
            const float og = sigm(v[3] + b3);
            const float cv = c[(size_t)row * HIDDEN + jg];
            const float cn = fg * cv + ig * cg;
            const float hn = og * tanh_fast(cn);
            out[(size_t)row * HIDDEN + jg] = hn;        // h_new
            out[HB + (size_t)row * HIDDEN + jg] = cn;   // c_new
        }
    }
}

// ---------- launcher ----------

extern "C" void kernel_launch(void* const* d_in, const int* in_sizes, int n_in,
                              void* d_out, int out_size, void* d_ws, size_t ws_size,
                              hipStream_t stream) {
    const float* x    = (const float*)d_in[0];
    const float* h    = (const float*)d_in[1];
    const float* c    = (const float*)d_in[2];
    const float* w_ih = (const float*)d_in[3];
    const float* w_hh = (const float*)d_in[4];
    const float* b_ih = (const float*)d_in[5];
    const float* b_hh = (const float*)d_in[6];
    float* out = (float*)d_out;

    const size_t XB_BYTES = (size_t)BATCH * KDIM * 2;   // 32 MB
    unsigned short* Xb = (unsigned short*)d_ws;
    unsigned short* Wt = (unsigned short*)((char*)d_ws + XB_BYTES);  // 64 MB

    hipLaunchKernelGGL(pack_x_kernel, dim3((size_t)BATCH * KDIM / 8 / 256), dim3(256), 0, stream,
                       x, h, Xb);
    hipLaunchKernelGGL(pack_w_kernel, dim3(KDIM / 64, NDIM / 32), dim3(256), 0, stream,
                       w_ih, w_hh, Wt);
    hipLaunchKernelGGL(gemm_kernel, dim3(NDIM / BN, BATCH / BM), dim3(256), 0, stream,
                       Xb, Wt, c, b_ih, b_hh, out);
}